// Round 6
// baseline (43.411 us; speedup 1.0000x reference)
//
#include <hip/hip_runtime.h>

// 3x3 median filter, zero padding, B=128, C=1, H=W=512, fp32.
// R5: 4 output rows per thread (6 input rows loaded once -> 1.5x L2-side
// read amplification, was 2x), two 4-px column windows per thread
// (cols 4*lane and 256+4*lane) so every load/store is a contiguous 1KiB
// wave segment. Horizontal halos via cross-lane shuffles. Median-of-9 =
// sorted-column trick with v_min3/v_med3/v_max3 (exact-select, absmax 0).
// Nontemporal coalesced stores + XCD-chunked block swizzle kept from R4.

typedef float f32x4 __attribute__((ext_vector_type(4)));

__device__ __forceinline__ float med3(float a, float b, float c) {
    return __builtin_amdgcn_fmed3f(a, b, c);
}
__device__ __forceinline__ float min3(float a, float b, float c) {
    return fminf(fminf(a, b), c);   // fuses to v_min3_f32
}
__device__ __forceinline__ float max3(float a, float b, float c) {
    return fmaxf(fmaxf(a, b), c);   // fuses to v_max3_f32
}

__global__ __launch_bounds__(256) void median3x3_kernel(
        const float* __restrict__ in, float* __restrict__ out) {
    const int W = 512, H = 512;
    int lane = threadIdx.x & 63;

    // XCD-chunked swizzle: 4096 blocks, 8 XCDs, round-robin dispatch ->
    // XCD x owns swizzled ids [x*512,(x+1)*512) = 32 contiguous images.
    int bid = blockIdx.x;
    int swz = (bid & 7) * 512 + (bid >> 3);

    int gw   = swz * 4 + (threadIdx.x >> 6);         // global wave id, 16384
    int yt   = gw & 127;                             // row-quad within image
    int bi   = gw >> 7;                              // image index 0..127
    int y0   = yt << 2;                              // first output row

    const float* base = in + (size_t)bi * H * W;

    // Input rows y0-1 .. y0+4. A = cols [4l,4l+4), B = cols [256+4l,256+4l+4).
    float A[6][4], B[6][4];
    float AL[6], AR[6], BL[6], BR[6];   // halo cols 4l-1, 4l+4, 256+4l-1, 256+4l+4

#pragma unroll
    for (int k = 0; k < 6; ++k) {
        int yy = y0 - 1 + k;
        if (yy >= 0 && yy < H) {                     // wave-uniform branch
            const float* rp = base + (size_t)yy * W;
            f32x4 va = *reinterpret_cast<const f32x4*>(rp + lane * 4);
            f32x4 vb = *reinterpret_cast<const f32x4*>(rp + 256 + lane * 4);
            A[k][0] = va.x; A[k][1] = va.y; A[k][2] = va.z; A[k][3] = va.w;
            B[k][0] = vb.x; B[k][1] = vb.y; B[k][2] = vb.z; B[k][3] = vb.w;
        } else {
#pragma unroll
            for (int c = 0; c < 4; ++c) { A[k][c] = 0.0f; B[k][c] = 0.0f; }
        }
    }

#pragma unroll
    for (int k = 0; k < 6; ++k) {
        float al    = __shfl_up  (A[k][3], 1, 64);   // lane-1's A3 == col 4l-1
        float ar    = __shfl_down(A[k][0], 1, 64);   // lane+1's A0 == col 4l+4
        float bl    = __shfl_up  (B[k][3], 1, 64);
        float br    = __shfl_down(B[k][0], 1, 64);
        float seamR = __shfl     (B[k][0], 0, 64);   // col 256 (lane 0's B0)
        float seamL = __shfl     (A[k][3], 63, 64);  // col 255 (lane 63's A3)
        AL[k] = (lane == 0)  ? 0.0f  : al;           // image left edge pad
        AR[k] = (lane == 63) ? seamR : ar;           // seam at col 255/256
        BL[k] = (lane == 0)  ? seamL : bl;
        BR[k] = (lane == 63) ? 0.0f  : br;           // image right edge pad
    }

    float* obase = out + ((size_t)bi * H + y0) * W;

#pragma unroll
    for (int r = 0; r < 4; ++r) {        // output row y0+r uses input rows r..r+2
        float lo[6], mi[6], hi[6];

        // window A: columns 4l-1 .. 4l+4
#pragma unroll
        for (int c = 0; c < 6; ++c) {
            float x0 = (c == 0) ? AL[r]     : (c == 5) ? AR[r]     : A[r][c - 1];
            float x1 = (c == 0) ? AL[r + 1] : (c == 5) ? AR[r + 1] : A[r + 1][c - 1];
            float x2 = (c == 0) ? AL[r + 2] : (c == 5) ? AR[r + 2] : A[r + 2][c - 1];
            lo[c] = min3(x0, x1, x2);
            mi[c] = med3(x0, x1, x2);
            hi[c] = max3(x0, x1, x2);
        }
        f32x4 oa;
        oa.x = med3(max3(lo[0], lo[1], lo[2]), med3(mi[0], mi[1], mi[2]), min3(hi[0], hi[1], hi[2]));
        oa.y = med3(max3(lo[1], lo[2], lo[3]), med3(mi[1], mi[2], mi[3]), min3(hi[1], hi[2], hi[3]));
        oa.z = med3(max3(lo[2], lo[3], lo[4]), med3(mi[2], mi[3], mi[4]), min3(hi[2], hi[3], hi[4]));
        oa.w = med3(max3(lo[3], lo[4], lo[5]), med3(mi[3], mi[4], mi[5]), min3(hi[3], hi[4], hi[5]));

        // window B: columns 256+4l-1 .. 256+4l+4
#pragma unroll
        for (int c = 0; c < 6; ++c) {
            float x0 = (c == 0) ? BL[r]     : (c == 5) ? BR[r]     : B[r][c - 1];
            float x1 = (c == 0) ? BL[r + 1] : (c == 5) ? BR[r + 1] : B[r + 1][c - 1];
            float x2 = (c == 0) ? BL[r + 2] : (c == 5) ? BR[r + 2] : B[r + 2][c - 1];
            lo[c] = min3(x0, x1, x2);
            mi[c] = med3(x0, x1, x2);
            hi[c] = max3(x0, x1, x2);
        }
        f32x4 ob;
        ob.x = med3(max3(lo[0], lo[1], lo[2]), med3(mi[0], mi[1], mi[2]), min3(hi[0], hi[1], hi[2]));
        ob.y = med3(max3(lo[1], lo[2], lo[3]), med3(mi[1], mi[2], mi[3]), min3(hi[1], hi[2], hi[3]));
        ob.z = med3(max3(lo[2], lo[3], lo[4]), med3(mi[2], mi[3], mi[4]), min3(hi[2], hi[3], hi[4]));
        ob.w = med3(max3(lo[3], lo[4], lo[5]), med3(mi[3], mi[4], mi[5]), min3(hi[3], hi[4], hi[5]));

        float* op = obase + (size_t)r * W;
        __builtin_nontemporal_store(oa, reinterpret_cast<f32x4*>(op + lane * 4));
        __builtin_nontemporal_store(ob, reinterpret_cast<f32x4*>(op + 256 + lane * 4));
    }
}

extern "C" void kernel_launch(void* const* d_in, const int* in_sizes, int n_in,
                              void* d_out, int out_size, void* d_ws, size_t ws_size,
                              hipStream_t stream) {
    const float* x = (const float*)d_in[0];
    float* out = (float*)d_out;

    // 128 images x 128 row-quads = 16384 waves = 4096 blocks of 4 waves.
    int blocks = 4096;
    median3x3_kernel<<<blocks, 256, 0, stream>>>(x, out);
}

// Round 7
// 41.849 us; speedup vs baseline: 1.0373x; 1.0373x over previous
//
#include <hip/hip_runtime.h>

// 3x3 median filter, zero padding, B=128, C=1, H=W=512, fp32.
// R4 config (best measured: 41.9 us) — reverted from R5's 4-row variant,
// which cut TLP (16k waves vs 32k) and regressed to 43.4 us.
//
// Each thread: 2 output rows x 8 px, as two 4-px windows (cols 4*lane and
// 256+4*lane) so every load/store instruction is a contiguous 1KiB wave
// segment. 4 input rows load once into registers, reused for both output
// rows. Horizontal halos via cross-lane shuffles. Median-of-9 = sorted-column
// trick with v_min3/v_med3/v_max3 (exact-select -> absmax 0).
// Nontemporal coalesced stores (full 64B lines, no amplification; keeps the
// write stream from evicting the L3-resident input) + XCD-chunked block
// swizzle (each XCD owns 16 whole images -> halo reuse is same-XCD L2 hits).

typedef float f32x4 __attribute__((ext_vector_type(4)));

__device__ __forceinline__ float med3(float a, float b, float c) {
    return __builtin_amdgcn_fmed3f(a, b, c);
}
__device__ __forceinline__ float min3(float a, float b, float c) {
    return fminf(fminf(a, b), c);   // fuses to v_min3_f32
}
__device__ __forceinline__ float max3(float a, float b, float c) {
    return fmaxf(fmaxf(a, b), c);   // fuses to v_max3_f32
}

__global__ __launch_bounds__(256) void median3x3_kernel(
        const float* __restrict__ in, float* __restrict__ out) {
    const int W = 512, H = 512;
    int lane = threadIdx.x & 63;

    // XCD-chunked swizzle: 8192 blocks, 8 XCDs, round-robin dispatch ->
    // XCD x gets swizzled ids [x*1024, (x+1)*1024) = 16 contiguous images.
    int bid = blockIdx.x;
    int swz = (bid & 7) * 1024 + (bid >> 3);

    int gw   = swz * 4 + (threadIdx.x >> 6);         // global wave id
    int yt   = gw & 255;                             // row-pair within image
    int bi   = gw >> 8;                              // image index 0..127
    int y0   = yt << 1;                              // first output row

    const float* base = in + (size_t)bi * H * W;

    // Input rows y0-1 .. y0+2. A = cols [4l,4l+4), B = cols [256+4l,256+4l+4).
    float A[4][4], B[4][4];
    float AL[4], AR[4], BL[4], BR[4];   // halo cols 4l-1, 4l+4, 256+4l-1, 256+4l+4

#pragma unroll
    for (int k = 0; k < 4; ++k) {
        int yy = y0 - 1 + k;
        if (yy >= 0 && yy < H) {                     // wave-uniform branch
            const float* rp = base + (size_t)yy * W;
            f32x4 va = *reinterpret_cast<const f32x4*>(rp + lane * 4);
            f32x4 vb = *reinterpret_cast<const f32x4*>(rp + 256 + lane * 4);
            A[k][0] = va.x; A[k][1] = va.y; A[k][2] = va.z; A[k][3] = va.w;
            B[k][0] = vb.x; B[k][1] = vb.y; B[k][2] = vb.z; B[k][3] = vb.w;
        } else {
#pragma unroll
            for (int c = 0; c < 4; ++c) { A[k][c] = 0.0f; B[k][c] = 0.0f; }
        }
    }

#pragma unroll
    for (int k = 0; k < 4; ++k) {
        float al    = __shfl_up  (A[k][3], 1, 64);   // lane-1's A3 == col 4l-1
        float ar    = __shfl_down(A[k][0], 1, 64);   // lane+1's A0 == col 4l+4
        float bl    = __shfl_up  (B[k][3], 1, 64);
        float br    = __shfl_down(B[k][0], 1, 64);
        float seamR = __shfl     (B[k][0], 0, 64);   // col 256 (lane 0's B0)
        float seamL = __shfl     (A[k][3], 63, 64);  // col 255 (lane 63's A3)
        AL[k] = (lane == 0)  ? 0.0f  : al;           // image left edge pad
        AR[k] = (lane == 63) ? seamR : ar;           // seam at col 255/256
        BL[k] = (lane == 0)  ? seamL : bl;
        BR[k] = (lane == 63) ? 0.0f  : br;           // image right edge pad
    }

    float* obase = out + ((size_t)bi * H + y0) * W;

#pragma unroll
    for (int r = 0; r < 2; ++r) {        // output rows y0+r, input rows r..r+2
        float lo[6], mi[6], hi[6];

        // window A: columns 4l-1 .. 4l+4
#pragma unroll
        for (int c = 0; c < 6; ++c) {
            float x0 = (c == 0) ? AL[r]     : (c == 5) ? AR[r]     : A[r][c - 1];
            float x1 = (c == 0) ? AL[r + 1] : (c == 5) ? AR[r + 1] : A[r + 1][c - 1];
            float x2 = (c == 0) ? AL[r + 2] : (c == 5) ? AR[r + 2] : A[r + 2][c - 1];
            lo[c] = min3(x0, x1, x2);
            mi[c] = med3(x0, x1, x2);
            hi[c] = max3(x0, x1, x2);
        }
        f32x4 oa;
        oa.x = med3(max3(lo[0], lo[1], lo[2]), med3(mi[0], mi[1], mi[2]), min3(hi[0], hi[1], hi[2]));
        oa.y = med3(max3(lo[1], lo[2], lo[3]), med3(mi[1], mi[2], mi[3]), min3(hi[1], hi[2], hi[3]));
        oa.z = med3(max3(lo[2], lo[3], lo[4]), med3(mi[2], mi[3], mi[4]), min3(hi[2], hi[3], hi[4]));
        oa.w = med3(max3(lo[3], lo[4], lo[5]), med3(mi[3], mi[4], mi[5]), min3(hi[3], hi[4], hi[5]));

        // window B: columns 256+4l-1 .. 256+4l+4
#pragma unroll
        for (int c = 0; c < 6; ++c) {
            float x0 = (c == 0) ? BL[r]     : (c == 5) ? BR[r]     : B[r][c - 1];
            float x1 = (c == 0) ? BL[r + 1] : (c == 5) ? BR[r + 1] : B[r + 1][c - 1];
            float x2 = (c == 0) ? BL[r + 2] : (c == 5) ? BR[r + 2] : B[r + 2][c - 1];
            lo[c] = min3(x0, x1, x2);
            mi[c] = med3(x0, x1, x2);
            hi[c] = max3(x0, x1, x2);
        }
        f32x4 ob;
        ob.x = med3(max3(lo[0], lo[1], lo[2]), med3(mi[0], mi[1], mi[2]), min3(hi[0], hi[1], hi[2]));
        ob.y = med3(max3(lo[1], lo[2], lo[3]), med3(mi[1], mi[2], mi[3]), min3(hi[1], hi[2], hi[3]));
        ob.z = med3(max3(lo[2], lo[3], lo[4]), med3(mi[2], mi[3], mi[4]), min3(hi[2], hi[3], hi[4]));
        ob.w = med3(max3(lo[3], lo[4], lo[5]), med3(mi[3], mi[4], mi[5]), min3(hi[3], hi[4], hi[5]));

        float* op = obase + (size_t)r * W;
        __builtin_nontemporal_store(oa, reinterpret_cast<f32x4*>(op + lane * 4));
        __builtin_nontemporal_store(ob, reinterpret_cast<f32x4*>(op + 256 + lane * 4));
    }
}

extern "C" void kernel_launch(void* const* d_in, const int* in_sizes, int n_in,
                              void* d_out, int out_size, void* d_ws, size_t ws_size,
                              hipStream_t stream) {
    const float* x = (const float*)d_in[0];
    float* out = (float*)d_out;

    // 128 images x 256 row-pairs = 32768 waves = 8192 blocks of 4 waves.
    int blocks = 8192;
    median3x3_kernel<<<blocks, 256, 0, stream>>>(x, out);
}